// Round 2
// baseline (2050.755 us; speedup 1.0000x reference)
//
#include <hip/hip_runtime.h>
#include <stdint.h>
#include <stddef.h>

// Problem constants
#define VOCAB 50000
#define EMB   128
#define HID   256
#define G4    1024   // 4*HID
#define BATCH 512
#define SEQ   256
#define NCHAIN 1024  // 2 sequences * 512 batch

// ---------- workspace layout (bytes) ----------
#define OFF_TABLE  0UL
#define SZ_TABLE   (50000UL*1024UL*2UL)            // 102,400,000  bf16 gate table (permuted cols)
#define OFF_WHHF   (OFF_TABLE + SZ_TABLE)
#define SZ_WHHF    (512UL*512UL*2UL)               // 524,288      w_hh B-fragments bf16
#define OFF_WIHF   (OFF_WHHF + SZ_WHHF)
#define SZ_WIHF    (256UL*512UL*2UL)               // 262,144      w_ih B-fragments bf16
#define OFF_BCOMB  (OFF_WIHF + SZ_WIHF)
#define SZ_BCOMB   (1024UL*4UL)                    // combined bias (permuted)
#define OFF_WHIDT  (OFF_BCOMB + SZ_BCOMB)
#define SZ_WHIDT   (512UL*256UL*4UL)               // w_hid transposed [512][256] f32
#define OFF_HOUT   (OFF_WHIDT + SZ_WHIDT)
#define SZ_HOUT    (1024UL*256UL*4UL)              // final h per chain, f32
// total ~104.8 MB

typedef short bf16x8 __attribute__((ext_vector_type(8)));
typedef short bf16x4 __attribute__((ext_vector_type(4)));
typedef float f32x4  __attribute__((ext_vector_type(4)));
typedef float f32x2  __attribute__((ext_vector_type(2)));

__device__ __forceinline__ unsigned short f2bf(float f) {
  union { float f; uint32_t u; } v; v.f = f;
  uint32_t r = (v.u + 0x7FFFu + ((v.u >> 16) & 1u)) >> 16;
  return (unsigned short)r;
}
__device__ __forceinline__ float bf2f(unsigned short h) {
  union { float f; uint32_t u; } v; v.u = ((uint32_t)h) << 16; return v.f;
}
__device__ __forceinline__ float fast_exp2(float x) { return __builtin_amdgcn_exp2f(x); }
__device__ __forceinline__ float fast_rcp(float x)  { return __builtin_amdgcn_rcpf(x); }
#define LOG2E 1.4426950408889634f
__device__ __forceinline__ float sigm(float x) {
  return fast_rcp(1.0f + fast_exp2(-LOG2E * x));
}
__device__ __forceinline__ float tanh_(float x) {
  float e = fast_exp2(2.0f * LOG2E * x);     // exp(2x)
  return 1.0f - 2.0f * fast_rcp(e + 1.0f);   // (e-1)/(e+1)
}

// gate permutation: wave w (0..7) owns local gates i (0..127);
// original gate index = (i>>5)*256 + w*32 + (i&31)   (blocks: i,f,g,o for j in [w*32, w*32+32))
__device__ __forceinline__ int gperm(int w, int i) {
  return ((i >> 5) << 8) + (w << 5) + (i & 31);
}

// LDS swizzles (byte-XOR per G4 to break b128 same-bank columns). Index in ushorts.
__device__ __forceinline__ int hswz(int m, int k) {          // h tile: row stride 256 bf16
  return ((m * 512 + k * 2) ^ ((m & 7) << 4)) >> 1;
}
__device__ __forceinline__ int aswz(int row, int k) {        // emb tile: row stride 128 bf16
  return ((row * 256 + k * 2) ^ ((row & 7) << 4)) >> 1;
}

// Shared A/B k-placement bijection within each 32-wide k block:
//   fragment position p = g*8 + e  holds true k with
//   hf = e>>2, v = g*4 + (e&3)  i.e.  k = (e>>2)*16 + g*4 + (e&3)   (+ base of block)
// Inverse (used when SCATTERING by true k): for k = hf*16 + v (hf=bit4, v=k&15):
//   p = (v>>2)*8 + hf*4 + (v&3)
// B fragments (k0) and A-side LDS stores (k1 staging, k2 h-write) all use THIS map,
// so the MFMA contraction pairs identical true-k on both sides (bug fixed this round).
__device__ __forceinline__ int kplace(int k) {   // k in [0,32), returns p in [0,32)
  int v = k & 15, hf = (k >> 4) & 1;
  return ((v >> 2) << 3) + (hf << 2) + (v & 3);
}

// ============================================================================
// k0: pack w_hh / w_ih into MFMA B-fragment layout (bf16), combined bias, w_hid^T
// ============================================================================
__global__ __launch_bounds__(256) void k0_prep(
    const float* __restrict__ w_ih, const float* __restrict__ w_hh,
    const float* __restrict__ b_ih, const float* __restrict__ b_hh,
    const float* __restrict__ w_hid,
    unsigned short* __restrict__ whhf, unsigned short* __restrict__ wihf,
    float* __restrict__ bcomb, float* __restrict__ whidT)
{
  int idx = blockIdx.x * 256 + threadIdx.x;
  if (idx < 262144) {                       // whhf: 512 frags x 512 ushorts
    int f = idx >> 9, r = idx & 511, l = r >> 3, e = r & 7;
    int w = f >> 6, nt = (f >> 3) & 7, ks = f & 7;
    int n = gperm(w, nt * 16 + (l & 15));
    int k = ks * 32 + ((e >> 2) << 4) + ((l >> 4) << 2) + (e & 3);
    whhf[idx] = f2bf(w_hh[n * HID + k]);
  } else if (idx < 262144 + 131072) {       // wihf: 256 frags x 512
    int i2 = idx - 262144;
    int f = i2 >> 9, r = i2 & 511, l = r >> 3, e = r & 7;
    int ks = f & 3, nt = (f >> 2) & 7, w = f >> 5;
    int n = gperm(w, nt * 16 + (l & 15));
    int k = ks * 32 + ((e >> 2) << 4) + ((l >> 4) << 2) + (e & 3);
    wihf[i2] = f2bf(w_ih[n * EMB + k]);
  } else if (idx < 262144 + 131072 + 1024) {
    int i2 = idx - (262144 + 131072);
    int w = i2 >> 7, ii = i2 & 127;
    int g = gperm(w, ii);
    bcomb[i2] = b_ih[g] + b_hh[g];
  } else if (idx < 262144 + 131072 + 1024 + 131072) {
    int i2 = idx - (262144 + 131072 + 1024);
    int k = i2 >> 8, rr = i2 & 255;
    whidT[i2] = w_hid[rr * 512 + k];        // w_hid [256][512] -> [512][256]
  }
}

// ============================================================================
// k1: gate table GEMM: table[v][p] = emb[v] . w_ih[G(p)] + bcomb[p]   (bf16 out)
//     M=50000 rows (64/block), N=1024 permuted cols, K=128.
// ============================================================================
__global__ __launch_bounds__(256, 4) void k1_table(
    const float* __restrict__ emb, const unsigned short* __restrict__ wihf,
    const float* __restrict__ bcomb, unsigned short* __restrict__ table2)
{
  __shared__ unsigned short a_lds[64 * 128];      // swizzled + k-placed bf16
  __shared__ unsigned short ostage[4 * 16 * 136]; // per-wave staging, padded rows
  const int tid = threadIdx.x;
  const int w = tid >> 6, l = tid & 63, r0 = l >> 4, c0 = l & 15;
  const int v0 = blockIdx.x * 64;

  // stage 64 emb rows as bf16, scattered into the SHARED k-placement map
  for (int idx = tid; idx < 8192; idx += 256) {
    int row = idx >> 7, k = idx & 127;
    int gr = v0 + row; if (gr >= VOCAB) gr = VOCAB - 1;
    float x = emb[(size_t)gr * EMB + k];
    int p = (k & ~31) + kplace(k & 31);
    a_lds[aswz(row, p)] = f2bf(x);
  }
  __syncthreads();

  bf16x8 af[4];
#pragma unroll
  for (int ks = 0; ks < 4; ++ks)
    af[ks] = *(const bf16x8*)&a_lds[aswz(w * 16 + c0, ks * 32 + r0 * 8)];

  unsigned short* ost = &ostage[w * 2176];
#pragma unroll 1
  for (int nb = 0; nb < 8; ++nb) {
    f32x4 acc[8];
#pragma unroll
    for (int nt = 0; nt < 8; ++nt) acc[nt] = (f32x4){0.f, 0.f, 0.f, 0.f};
#pragma unroll
    for (int ks = 0; ks < 4; ++ks) {
#pragma unroll
      for (int nt = 0; nt < 8; ++nt) {
        bf16x8 bv = *(const bf16x8*)(wihf + ((((nb * 8 + nt) * 4) + ks) << 9) + (l << 3));
        acc[nt] = __builtin_amdgcn_mfma_f32_16x16x32_bf16(af[ks], bv, acc[nt], 0, 0, 0);
      }
    }
#pragma unroll
    for (int nt = 0; nt < 8; ++nt) {
      float bias = bcomb[nb * 128 + nt * 16 + c0];
#pragma unroll
      for (int reg = 0; reg < 4; ++reg)
        ost[(r0 * 4 + reg) * 136 + nt * 16 + c0] = f2bf(acc[nt][reg] + bias);
    }
    asm volatile("s_waitcnt lgkmcnt(0)" ::: "memory");
#pragma unroll
    for (int i = 0; i < 4; ++i) {
      int idx = i * 64 + l;
      int row = idx >> 4, seg = idx & 15;
      int v = v0 + w * 16 + row;
      if (v < VOCAB)
        *(bf16x8*)(table2 + (size_t)v * 1024 + nb * 128 + seg * 8) =
            *(const bf16x8*)&ost[row * 136 + seg * 8];
    }
    __syncthreads();
  }
}

// ============================================================================
// k2: the recurrence. 64 blocks x 512 threads (8 waves). Block owns 16 chains.
//     Wave w owns gates {i,f,g,o} for j in [w*32, w*32+32)  (4 n-tile pairs).
//     w_hh slice: n-tiles 0..3 register-resident, 4..7 streamed from L2.
// ============================================================================
__global__ __launch_bounds__(512, 2) void k2_lstm(
    const int* __restrict__ s1, const int* __restrict__ s2,
    const unsigned short* __restrict__ table2,
    const unsigned short* __restrict__ whhf,
    float* __restrict__ h_out)
{
  __shared__ unsigned short h_lds[16 * 256];     // swizzled + k-placed bf16
  __shared__ unsigned short tok_lds[16 * 256];   // tokens as u16
  __shared__ unsigned short xg_lds[8 * 16 * 136];// per-wave xg slices, padded rows

  const int tid = threadIdx.x;
  const int w = tid >> 6, l = tid & 63;
  const int r0 = l >> 4, c0 = l & 15;
  const int blk = blockIdx.x;
  const int xg_chain = l >> 2;        // 4 lanes per chain
  const int xg_seg = l & 3;

  // preload tokens (u16) + zero h
  for (int idx = tid; idx < 4096; idx += 512) {
    int chain = blk * 16 + (idx >> 8);
    const int* sp = (chain >= 512) ? s2 : s1;
    tok_lds[idx] = (unsigned short)sp[(chain & 511) * SEQ + (idx & 255)];
    h_lds[idx] = 0;
  }
  __syncthreads();

  const unsigned short* whW = whhf + w * 32768;  // this wave's 64 frags

  // resident weights: n-tiles 0..3, all 8 k-steps  (128 VGPRs)
  bf16x8 whr[4][8];
#pragma unroll
  for (int nt = 0; nt < 4; ++nt)
#pragma unroll
    for (int ks = 0; ks < 8; ++ks)
      whr[nt][ks] = *(const bf16x8*)(whW + ((nt * 8 + ks) << 9) + (l << 3));

  bf16x8 bstr[2][4];
  bf16x8 X0, X1, X2, X3;
  {
    int tok0 = tok_lds[xg_chain * 256 + 0];
    const unsigned short* xr = table2 + (size_t)tok0 * 1024 + w * 128;
    X0 = *(const bf16x8*)(xr + (xg_seg) * 8);
    X1 = *(const bf16x8*)(xr + (xg_seg + 4) * 8);
    X2 = *(const bf16x8*)(xr + (xg_seg + 8) * 8);
    X3 = *(const bf16x8*)(xr + (xg_seg + 12) * 8);
#pragma unroll
    for (int nt = 0; nt < 4; ++nt)
      bstr[0][nt] = *(const bf16x8*)(whW + (((nt + 4) * 8 + 0) << 9) + (l << 3));
  }

  float c_st[8];
#pragma unroll
  for (int i = 0; i < 8; ++i) c_st[i] = 0.f;
  float hv[8];
#pragma unroll
  for (int i = 0; i < 8; ++i) hv[i] = 0.f;

#pragma unroll 1
  for (int t = 0; t < SEQ; ++t) {
    // store this step's xg into per-wave LDS slice
    {
      int base = w * 2176 + xg_chain * 136;
      *(bf16x8*)&xg_lds[base + (xg_seg) * 8] = X0;
      *(bf16x8*)&xg_lds[base + (xg_seg + 4) * 8] = X1;
      *(bf16x8*)&xg_lds[base + (xg_seg + 8) * 8] = X2;
      *(bf16x8*)&xg_lds[base + (xg_seg + 12) * 8] = X3;
    }

    f32x4 acc[8];
#pragma unroll
    for (int nt = 0; nt < 8; ++nt) acc[nt] = (f32x4){0.f, 0.f, 0.f, 0.f};

    bf16x8 aab[2];
    aab[0] = *(const bf16x8*)&h_lds[hswz(c0, 0 * 32 + r0 * 8)];
#pragma unroll
    for (int ks = 0; ks < 8; ++ks) {
      if (ks < 7) {
        aab[(ks + 1) & 1] = *(const bf16x8*)&h_lds[hswz(c0, (ks + 1) * 32 + r0 * 8)];
#pragma unroll
        for (int nt = 0; nt < 4; ++nt)
          bstr[(ks + 1) & 1][nt] =
              *(const bf16x8*)(whW + (((nt + 4) * 8 + (ks + 1)) << 9) + (l << 3));
      }
      bf16x8 av = aab[ks & 1];
#pragma unroll
      for (int nt = 0; nt < 4; ++nt)
        acc[nt] = __builtin_amdgcn_mfma_f32_16x16x32_bf16(av, whr[nt][ks], acc[nt], 0, 0, 0);
#pragma unroll
      for (int nt = 0; nt < 4; ++nt)
        acc[nt + 4] = __builtin_amdgcn_mfma_f32_16x16x32_bf16(av, bstr[ks & 1][nt], acc[nt + 4], 0, 0, 0);
    }

    // prefetch next step's xg + streamed ks0 (hides under elementwise + barriers)
    if (t + 1 < SEQ) {
      int tok = tok_lds[xg_chain * 256 + (t + 1)];
      const unsigned short* xr = table2 + (size_t)tok * 1024 + w * 128;
      X0 = *(const bf16x8*)(xr + (xg_seg) * 8);
      X1 = *(const bf16x8*)(xr + (xg_seg + 4) * 8);
      X2 = *(const bf16x8*)(xr + (xg_seg + 8) * 8);
      X3 = *(const bf16x8*)(xr + (xg_seg + 12) * 8);
#pragma unroll
      for (int nt = 0; nt < 4; ++nt)
        bstr[0][nt] = *(const bf16x8*)(whW + (((nt + 4) * 8 + 0) << 9) + (l << 3));
    }

    // gates -> c,h (all in-wave; c stays in f32 registers for all 256 steps)
    asm volatile("s_waitcnt lgkmcnt(0)" ::: "memory");
#pragma unroll
    for (int hf = 0; hf < 2; ++hf) {
#pragma unroll
      for (int q = 0; q < 4; ++q) {
        int m = r0 * 4 + q;
        int xb = w * 2176 + m * 136 + c0;
        float xi = bf2f(xg_lds[xb + (0 * 2 + hf) * 16]);
        float xf = bf2f(xg_lds[xb + (1 * 2 + hf) * 16]);
        float xgv = bf2f(xg_lds[xb + (2 * 2 + hf) * 16]);
        float xo = bf2f(xg_lds[xb + (3 * 2 + hf) * 16]);
        float iv = sigm(acc[0 + hf][q] + xi);
        float fv = sigm(acc[2 + hf][q] + xf);
        float gv = tanh_(acc[4 + hf][q] + xgv);
        float ov = sigm(acc[6 + hf][q] + xo);
        int cs = hf * 4 + q;
        float c = fv * c_st[cs] + iv * gv;
        c_st[cs] = c;
        hv[cs] = ov * tanh_(c);
      }
    }

    __syncthreads();   // all waves done reading h(t-1)
#pragma unroll
    for (int hf = 0; hf < 2; ++hf)
#pragma unroll
      for (int q = 0; q < 4; ++q) {
        int m = r0 * 4 + q;
        // original j = w*32 + hf*16 + c0 -> SHARED k-placement within block w
        int qk = (w << 5) + ((c0 >> 2) << 3) + (hf << 2) + (c0 & 3);
        h_lds[hswz(m, qk)] = f2bf(hv[hf * 4 + q]);
      }
    __syncthreads();   // h(t) visible
  }

  // final h (f32, pre-rounding) -> h_out[chain][j]
#pragma unroll
  for (int hf = 0; hf < 2; ++hf)
#pragma unroll
    for (int q = 0; q < 4; ++q) {
      int m = r0 * 4 + q;
      int j = w * 32 + hf * 16 + c0;
      h_out[(size_t)(blk * 16 + m) * HID + j] = hv[hf * 4 + q];
    }
}

// ============================================================================
// k3: head: hidden = relu([h1,h2] @ w_hid^T + b_hid); out = hidden @ w_out^T + b_out
// ============================================================================
__global__ __launch_bounds__(256, 4) void k3_head(
    const float* __restrict__ h_out, const float* __restrict__ whidT,
    const float* __restrict__ b_hid, const float* __restrict__ w_out,
    const float* __restrict__ b_out, float* __restrict__ out)
{
  __shared__ float cat[8 * 512];
  __shared__ float hred[8 * 256];
  __shared__ float pred[4 * 24];
  const int tid = threadIdx.x;
  const int b0 = blockIdx.x * 8;

  for (int idx = tid; idx < 4096; idx += 256) {
    int r8 = idx >> 9, kk = idx & 511;
    float v = (kk < 256) ? h_out[(size_t)(b0 + r8) * HID + kk]
                         : h_out[(size_t)(512 + b0 + r8) * HID + (kk - 256)];
    cat[idx] = v;
  }
  __syncthreads();

  const int r = tid;
  float acc[8];
#pragma unroll
  for (int bb = 0; bb < 8; ++bb) acc[bb] = 0.f;
  for (int k = 0; k < 512; k += 4) {
    float w0 = whidT[(k + 0) * 256 + r];
    float w1 = whidT[(k + 1) * 256 + r];
    float w2 = whidT[(k + 2) * 256 + r];
    float w3 = whidT[(k + 3) * 256 + r];
#pragma unroll
    for (int bb = 0; bb < 8; ++bb) {
      f32x4 cv = *(const f32x4*)&cat[bb * 512 + k];
      acc[bb] += cv[0] * w0 + cv[1] * w1 + cv[2] * w2 + cv[3] * w3;
    }
  }
  float bh = b_hid[r];
#pragma unroll
  for (int bb = 0; bb < 8; ++bb) hred[bb * 256 + r] = fmaxf(acc[bb] + bh, 0.f);
  __syncthreads();

  const int wv = tid >> 6, l = tid & 63;
  float wo0 = w_out[0 * 256 + r], wo1 = w_out[1 * 256 + r], wo2 = w_out[2 * 256 + r];
#pragma unroll 1
  for (int bb = 0; bb < 8; ++bb) {
    float h = hred[bb * 256 + r];
    float p0 = h * wo0, p1 = h * wo1, p2 = h * wo2;
#pragma unroll
    for (int off = 32; off > 0; off >>= 1) {
      p0 += __shfl_down(p0, off, 64);
      p1 += __shfl_down(p1, off, 64);
      p2 += __shfl_down(p2, off, 64);
    }
    if (l == 0) {
      pred[wv * 24 + bb * 3 + 0] = p0;
      pred[wv * 24 + bb * 3 + 1] = p1;
      pred[wv * 24 + bb * 3 + 2] = p2;
    }
  }
  __syncthreads();
  if (tid < 24) {
    int bb = tid / 3, o = tid % 3;
    float s = pred[0 * 24 + tid] + pred[1 * 24 + tid] + pred[2 * 24 + tid] + pred[3 * 24 + tid]
              + b_out[o];
    out[(size_t)(b0 + bb) * 3 + o] = s;
  }
}

// ============================================================================
extern "C" void kernel_launch(void* const* d_in, const int* in_sizes, int n_in,
                              void* d_out, int out_size, void* d_ws, size_t ws_size,
                              hipStream_t stream) {
  (void)in_sizes; (void)n_in; (void)out_size; (void)ws_size; // needs ~105 MB ws
  const int*   s1    = (const int*)d_in[0];
  const int*   s2    = (const int*)d_in[1];
  const float* emb   = (const float*)d_in[2];
  const float* w_ih  = (const float*)d_in[3];
  const float* w_hh  = (const float*)d_in[4];
  const float* b_ih  = (const float*)d_in[5];
  const float* b_hh  = (const float*)d_in[6];
  const float* w_hid = (const float*)d_in[7];
  const float* b_hid = (const float*)d_in[8];
  const float* w_out = (const float*)d_in[9];
  const float* b_out = (const float*)d_in[10];
  char* ws = (char*)d_ws;
  unsigned short* table2 = (unsigned short*)(ws + OFF_TABLE);
  unsigned short* whhf   = (unsigned short*)(ws + OFF_WHHF);
  unsigned short* wihf   = (unsigned short*)(ws + OFF_WIHF);
  float* bcomb = (float*)(ws + OFF_BCOMB);
  float* whidT = (float*)(ws + OFF_WHIDT);
  float* h_out = (float*)(ws + OFF_HOUT);
  float* outp  = (float*)d_out;

  k0_prep<<<dim3(2052), dim3(256), 0, stream>>>(w_ih, w_hh, b_ih, b_hh, w_hid,
                                                whhf, wihf, bcomb, whidT);
  k1_table<<<dim3(782), dim3(256), 0, stream>>>(emb, wihf, bcomb, table2);
  k2_lstm<<<dim3(64), dim3(512), 0, stream>>>(s1, s2, table2, whhf, h_out);
  k3_head<<<dim3(64), dim3(256), 0, stream>>>(h_out, whidT, b_hid, w_out, b_out, outp);
}

// Round 3
// 1532.877 us; speedup vs baseline: 1.3378x; 1.3378x over previous
//
#include <hip/hip_runtime.h>
#include <stdint.h>
#include <stddef.h>

// Problem constants
#define VOCAB 50000
#define EMB   128
#define HID   256
#define G4    1024   // 4*HID
#define BATCH 512
#define SEQ   256
#define NCHAIN 1024  // 2 sequences * 512 batch

// ---------- workspace layout (bytes) ----------
#define OFF_TABLE  0UL
#define SZ_TABLE   (50000UL*1024UL*2UL)            // 102,400,000  bf16 gate table (permuted cols)
#define OFF_WHHF   (OFF_TABLE + SZ_TABLE)
#define SZ_WHHF    (512UL*512UL*2UL)               // 524,288      w_hh B-fragments bf16
#define OFF_WIHF   (OFF_WHHF + SZ_WHHF)
#define SZ_WIHF    (256UL*512UL*2UL)               // 262,144      w_ih B-fragments bf16
#define OFF_BCOMB  (OFF_WIHF + SZ_WIHF)
#define SZ_BCOMB   (1024UL*4UL)                    // combined bias (permuted)
#define OFF_WHIDT  (OFF_BCOMB + SZ_BCOMB)
#define SZ_WHIDT   (512UL*256UL*4UL)               // w_hid transposed [512][256] f32
#define OFF_HOUT   (OFF_WHIDT + SZ_WHIDT)
#define SZ_HOUT    (1024UL*256UL*4UL)              // final h per chain, f32
// total ~104.8 MB

typedef short bf16x8 __attribute__((ext_vector_type(8)));
typedef short bf16x4 __attribute__((ext_vector_type(4)));
typedef float f32x4  __attribute__((ext_vector_type(4)));
typedef float f32x2  __attribute__((ext_vector_type(2)));

__device__ __forceinline__ unsigned short f2bf(float f) {
  union { float f; uint32_t u; } v; v.f = f;
  uint32_t r = (v.u + 0x7FFFu + ((v.u >> 16) & 1u)) >> 16;
  return (unsigned short)r;
}
__device__ __forceinline__ float bf2f(unsigned short h) {
  union { float f; uint32_t u; } v; v.u = ((uint32_t)h) << 16; return v.f;
}
__device__ __forceinline__ float fast_exp2(float x) { return __builtin_amdgcn_exp2f(x); }
__device__ __forceinline__ float fast_rcp(float x)  { return __builtin_amdgcn_rcpf(x); }
#define LOG2E 1.4426950408889634f
__device__ __forceinline__ float sigm(float x) {
  return fast_rcp(1.0f + fast_exp2(-LOG2E * x));
}
__device__ __forceinline__ float tanh_(float x) {
  float e = fast_exp2(2.0f * LOG2E * x);     // exp(2x)
  return 1.0f - 2.0f * fast_rcp(e + 1.0f);   // (e-1)/(e+1)
}

// gate permutation: wave w (0..7) owns local gates i (0..127);
// original gate index = (i>>5)*256 + w*32 + (i&31)   (blocks: i,f,g,o for j in [w*32, w*32+32))
__device__ __forceinline__ int gperm(int w, int i) {
  return ((i >> 5) << 8) + (w << 5) + (i & 31);
}

// LDS swizzles (byte-XOR per G4 to break b128 same-bank columns). Index in ushorts.
__device__ __forceinline__ int hswz(int m, int k) {          // h tile: row stride 256 bf16
  return ((m * 512 + k * 2) ^ ((m & 7) << 4)) >> 1;
}
__device__ __forceinline__ int aswz(int row, int k) {        // emb tile: row stride 128 bf16
  return ((row * 256 + k * 2) ^ ((row & 7) << 4)) >> 1;
}

// Shared A/B k-placement bijection within each 32-wide k block (A and B use the SAME
// map so the MFMA contraction pairs identical true-k on both sides; dot products are
// permutation-invariant so the true HW k-map is irrelevant):
//   scatter by true k: k = hf*16 + v (hf=bit4, v=k&15) -> p = (v>>2)*8 + hf*4 + (v&3)
__device__ __forceinline__ int kplace(int k) {   // k in [0,32), returns p in [0,32)
  int v = k & 15, hf = (k >> 4) & 1;
  return ((v >> 2) << 3) + (hf << 2) + (v & 3);
}

// ============================================================================
// k0: pack w_hh / w_ih into MFMA B-fragment layout (bf16), combined bias, w_hid^T
// ============================================================================
__global__ __launch_bounds__(256) void k0_prep(
    const float* __restrict__ w_ih, const float* __restrict__ w_hh,
    const float* __restrict__ b_ih, const float* __restrict__ b_hh,
    const float* __restrict__ w_hid,
    unsigned short* __restrict__ whhf, unsigned short* __restrict__ wihf,
    float* __restrict__ bcomb, float* __restrict__ whidT)
{
  int idx = blockIdx.x * 256 + threadIdx.x;
  if (idx < 262144) {                       // whhf: 512 frags x 512 ushorts
    int f = idx >> 9, r = idx & 511, l = r >> 3, e = r & 7;
    int w = f >> 6, nt = (f >> 3) & 7, ks = f & 7;
    int n = gperm(w, nt * 16 + (l & 15));
    int k = ks * 32 + ((e >> 2) << 4) + ((l >> 4) << 2) + (e & 3);
    whhf[idx] = f2bf(w_hh[n * HID + k]);
  } else if (idx < 262144 + 131072) {       // wihf: 256 frags x 512
    int i2 = idx - 262144;
    int f = i2 >> 9, r = i2 & 511, l = r >> 3, e = r & 7;
    int ks = f & 3, nt = (f >> 2) & 7, w = f >> 5;
    int n = gperm(w, nt * 16 + (l & 15));
    int k = ks * 32 + ((e >> 2) << 4) + ((l >> 4) << 2) + (e & 3);
    wihf[i2] = f2bf(w_ih[n * EMB + k]);
  } else if (idx < 262144 + 131072 + 1024) {
    int i2 = idx - (262144 + 131072);
    int w = i2 >> 7, ii = i2 & 127;
    int g = gperm(w, ii);
    bcomb[i2] = b_ih[g] + b_hh[g];
  } else if (idx < 262144 + 131072 + 1024 + 131072) {
    int i2 = idx - (262144 + 131072 + 1024);
    int k = i2 >> 8, rr = i2 & 255;
    whidT[i2] = w_hid[rr * 512 + k];        // w_hid [256][512] -> [512][256]
  }
}

// ============================================================================
// k1: gate table GEMM: table[v][p] = emb[v] . w_ih[G(p)] + bcomb[p]   (bf16 out)
//     M=50000 rows (64/block), N=1024 permuted cols, K=128.
// ============================================================================
__global__ __launch_bounds__(256, 4) void k1_table(
    const float* __restrict__ emb, const unsigned short* __restrict__ wihf,
    const float* __restrict__ bcomb, unsigned short* __restrict__ table2)
{
  __shared__ unsigned short a_lds[64 * 128];      // swizzled + k-placed bf16
  __shared__ unsigned short ostage[4 * 16 * 136]; // per-wave staging, padded rows
  const int tid = threadIdx.x;
  const int w = tid >> 6, l = tid & 63, r0 = l >> 4, c0 = l & 15;
  const int v0 = blockIdx.x * 64;

  // stage 64 emb rows as bf16, scattered into the SHARED k-placement map
  for (int idx = tid; idx < 8192; idx += 256) {
    int row = idx >> 7, k = idx & 127;
    int gr = v0 + row; if (gr >= VOCAB) gr = VOCAB - 1;
    float x = emb[(size_t)gr * EMB + k];
    int p = (k & ~31) + kplace(k & 31);
    a_lds[aswz(row, p)] = f2bf(x);
  }
  __syncthreads();

  bf16x8 af[4];
#pragma unroll
  for (int ks = 0; ks < 4; ++ks)
    af[ks] = *(const bf16x8*)&a_lds[aswz(w * 16 + c0, ks * 32 + r0 * 8)];

  unsigned short* ost = &ostage[w * 2176];
#pragma unroll 1
  for (int nb = 0; nb < 8; ++nb) {
    f32x4 acc[8];
#pragma unroll
    for (int nt = 0; nt < 8; ++nt) acc[nt] = (f32x4){0.f, 0.f, 0.f, 0.f};
#pragma unroll
    for (int ks = 0; ks < 4; ++ks) {
#pragma unroll
      for (int nt = 0; nt < 8; ++nt) {
        bf16x8 bv = *(const bf16x8*)(wihf + ((((nb * 8 + nt) * 4) + ks) << 9) + (l << 3));
        acc[nt] = __builtin_amdgcn_mfma_f32_16x16x32_bf16(af[ks], bv, acc[nt], 0, 0, 0);
      }
    }
#pragma unroll
    for (int nt = 0; nt < 8; ++nt) {
      float bias = bcomb[nb * 128 + nt * 16 + c0];
#pragma unroll
      for (int reg = 0; reg < 4; ++reg)
        ost[(r0 * 4 + reg) * 136 + nt * 16 + c0] = f2bf(acc[nt][reg] + bias);
    }
    asm volatile("s_waitcnt lgkmcnt(0)" ::: "memory");
#pragma unroll
    for (int i = 0; i < 4; ++i) {
      int idx = i * 64 + l;
      int row = idx >> 4, seg = idx & 15;
      int v = v0 + w * 16 + row;
      if (v < VOCAB)
        *(bf16x8*)(table2 + (size_t)v * 1024 + nb * 128 + seg * 8) =
            *(const bf16x8*)&ost[row * 136 + seg * 8];
    }
    __syncthreads();
  }
}

// ============================================================================
// k2: the recurrence. 64 blocks x 512 threads (8 waves). Block owns 16 chains.
//     Wave w owns gates {i,f,g,o} for j in [w*32, w*32+32) = 8 n-tiles of 16.
//     Weight residency (frag f = nt*8+ks, 64 frags/wave, 1 KB each):
//       nt 0..2  (24 frags) : VGPR-resident          (96 regs)
//       nt 3, nt4 ks<4 (12) : LDS-resident           (96 KB)
//       nt4 ks>=4, nt 5..7  : streamed from L2 each step, double-buffered
//     Budget ~215 VGPR (cap 256 via __launch_bounds__(512) -- NO 2nd arg;
//     (512,2) empirically capped VGPR at 128 and spilled everything).
// ============================================================================
__global__ __launch_bounds__(512) void k2_lstm(
    const int* __restrict__ s1, const int* __restrict__ s2,
    const unsigned short* __restrict__ table2,
    const unsigned short* __restrict__ whhf,
    float* __restrict__ h_out)
{
  __shared__ unsigned short h_lds[16 * 256];      // 8 KB  swizzled + k-placed bf16
  __shared__ unsigned short tok_lds[16 * 256];    // 8 KB  tokens as u16
  __shared__ unsigned short xg_lds[8 * 16 * 136]; // 34.8 KB per-wave xg slices
  __shared__ unsigned short w_lds[8 * 12 * 512];  // 96 KB  12 weight frags per wave

  const int tid = threadIdx.x;
  const int w = tid >> 6, l = tid & 63;
  const int r0 = l >> 4, c0 = l & 15;
  const int blk = blockIdx.x;
  const int xg_chain = l >> 2;        // 4 lanes per chain
  const int xg_seg = l & 3;

  // preload tokens (u16) + zero h
  for (int idx = tid; idx < 4096; idx += 512) {
    int chain = blk * 16 + (idx >> 8);
    const int* sp = (chain >= 512) ? s2 : s1;
    tok_lds[idx] = (unsigned short)sp[(chain & 511) * SEQ + (idx & 255)];
    h_lds[idx] = 0;
  }

  const unsigned short* whW = whhf + w * 32768;  // this wave's 64 frags
  unsigned short* wl = &w_lds[w * 6144];

  // stage LDS-resident frags 24..35 (nt3 all ks, nt4 ks0..3)
#pragma unroll
  for (int j = 0; j < 12; ++j) {
    bf16x8 v = *(const bf16x8*)(whW + ((24 + j) << 9) + (l << 3));
    *(bf16x8*)&wl[j * 512 + (l << 3)] = v;
  }

  // VGPR-resident frags: nt 0..2, all ks (96 VGPRs)
  bf16x8 whr[24];
#pragma unroll
  for (int f = 0; f < 24; ++f)
    whr[f] = *(const bf16x8*)(whW + (f << 9) + (l << 3));

  // streamed double-buffer: slot 0..2 = nt 5,6,7; slot 3 = nt4 (ks>=4 only)
  bf16x8 sbuf[2][4];
#pragma unroll
  for (int s = 0; s < 3; ++s)
    sbuf[0][s] = *(const bf16x8*)(whW + (((s + 5) * 8 + 0) << 9) + (l << 3));

  __syncthreads();

  // first xg prefetch
  bf16x8 X0, X1, X2, X3;
  {
    int tok0 = tok_lds[xg_chain * 256 + 0];
    const unsigned short* xr = table2 + (size_t)tok0 * 1024 + w * 128;
    X0 = *(const bf16x8*)(xr + (xg_seg) * 8);
    X1 = *(const bf16x8*)(xr + (xg_seg + 4) * 8);
    X2 = *(const bf16x8*)(xr + (xg_seg + 8) * 8);
    X3 = *(const bf16x8*)(xr + (xg_seg + 12) * 8);
  }

  float c_st[8], hv[8];
#pragma unroll
  for (int i = 0; i < 8; ++i) { c_st[i] = 0.f; hv[i] = 0.f; }

#pragma unroll 1
  for (int t = 0; t < SEQ; ++t) {
    // store this step's xg into per-wave LDS slice
    {
      int base = w * 2176 + xg_chain * 136;
      *(bf16x8*)&xg_lds[base + (xg_seg) * 8] = X0;
      *(bf16x8*)&xg_lds[base + (xg_seg + 4) * 8] = X1;
      *(bf16x8*)&xg_lds[base + (xg_seg + 8) * 8] = X2;
      *(bf16x8*)&xg_lds[base + (xg_seg + 12) * 8] = X3;
    }

    f32x4 acc[8];
#pragma unroll
    for (int nt = 0; nt < 8; ++nt) acc[nt] = (f32x4){0.f, 0.f, 0.f, 0.f};

#pragma unroll
    for (int ks = 0; ks < 8; ++ks) {
      // prefetch next ks's streamed frags (or next step's ks0 at ks==7)
      int kn = (ks + 1) & 7;
      int bn = kn & 1;
#pragma unroll
      for (int s = 0; s < 3; ++s)
        sbuf[bn][s] = *(const bf16x8*)(whW + (((s + 5) * 8 + kn) << 9) + (l << 3));
      if (ks >= 3 && ks < 7)
        sbuf[bn][3] = *(const bf16x8*)(whW + ((4 * 8 + kn) << 9) + (l << 3));

      bf16x8 av = *(const bf16x8*)&h_lds[hswz(c0, ks * 32 + r0 * 8)];
      // nt 0..2 from VGPR
      acc[0] = __builtin_amdgcn_mfma_f32_16x16x32_bf16(av, whr[0 * 8 + ks], acc[0], 0, 0, 0);
      acc[1] = __builtin_amdgcn_mfma_f32_16x16x32_bf16(av, whr[1 * 8 + ks], acc[1], 0, 0, 0);
      acc[2] = __builtin_amdgcn_mfma_f32_16x16x32_bf16(av, whr[2 * 8 + ks], acc[2], 0, 0, 0);
      // nt 3 from LDS
      {
        bf16x8 bv = *(const bf16x8*)&wl[ks * 512 + (l << 3)];
        acc[3] = __builtin_amdgcn_mfma_f32_16x16x32_bf16(av, bv, acc[3], 0, 0, 0);
      }
      // nt 4: LDS for ks<4, streamed for ks>=4
      if (ks < 4) {
        bf16x8 bv = *(const bf16x8*)&wl[(8 + ks) * 512 + (l << 3)];
        acc[4] = __builtin_amdgcn_mfma_f32_16x16x32_bf16(av, bv, acc[4], 0, 0, 0);
      } else {
        acc[4] = __builtin_amdgcn_mfma_f32_16x16x32_bf16(av, sbuf[ks & 1][3], acc[4], 0, 0, 0);
      }
      // nt 5..7 streamed
      acc[5] = __builtin_amdgcn_mfma_f32_16x16x32_bf16(av, sbuf[ks & 1][0], acc[5], 0, 0, 0);
      acc[6] = __builtin_amdgcn_mfma_f32_16x16x32_bf16(av, sbuf[ks & 1][1], acc[6], 0, 0, 0);
      acc[7] = __builtin_amdgcn_mfma_f32_16x16x32_bf16(av, sbuf[ks & 1][2], acc[7], 0, 0, 0);
    }

    // prefetch next step's xg (hides under elementwise + barriers)
    if (t + 1 < SEQ) {
      int tok = tok_lds[xg_chain * 256 + (t + 1)];
      const unsigned short* xr = table2 + (size_t)tok * 1024 + w * 128;
      X0 = *(const bf16x8*)(xr + (xg_seg) * 8);
      X1 = *(const bf16x8*)(xr + (xg_seg + 4) * 8);
      X2 = *(const bf16x8*)(xr + (xg_seg + 8) * 8);
      X3 = *(const bf16x8*)(xr + (xg_seg + 12) * 8);
    }

    // gates -> c,h (all in-wave; c stays in f32 registers for all 256 steps)
    asm volatile("s_waitcnt lgkmcnt(0)" ::: "memory");
#pragma unroll
    for (int hf = 0; hf < 2; ++hf) {
#pragma unroll
      for (int q = 0; q < 4; ++q) {
        int m = r0 * 4 + q;
        int xb = w * 2176 + m * 136 + c0;
        float xi = bf2f(xg_lds[xb + (0 * 2 + hf) * 16]);
        float xf = bf2f(xg_lds[xb + (1 * 2 + hf) * 16]);
        float xgv = bf2f(xg_lds[xb + (2 * 2 + hf) * 16]);
        float xo = bf2f(xg_lds[xb + (3 * 2 + hf) * 16]);
        float iv = sigm(acc[0 + hf][q] + xi);
        float fv = sigm(acc[2 + hf][q] + xf);
        float gv = tanh_(acc[4 + hf][q] + xgv);
        float ov = sigm(acc[6 + hf][q] + xo);
        int cs = hf * 4 + q;
        float c = fv * c_st[cs] + iv * gv;
        c_st[cs] = c;
        hv[cs] = ov * tanh_(c);
      }
    }

    __syncthreads();   // all waves done reading h(t-1)
#pragma unroll
    for (int hf = 0; hf < 2; ++hf)
#pragma unroll
      for (int q = 0; q < 4; ++q) {
        int m = r0 * 4 + q;
        // original j = w*32 + hf*16 + c0 -> SHARED k-placement within block w
        int qk = (w << 5) + ((c0 >> 2) << 3) + (hf << 2) + (c0 & 3);
        h_lds[hswz(m, qk)] = f2bf(hv[hf * 4 + q]);
      }
    __syncthreads();   // h(t) visible
  }

  // final h (f32, pre-rounding) -> h_out[chain][j]
#pragma unroll
  for (int hf = 0; hf < 2; ++hf)
#pragma unroll
    for (int q = 0; q < 4; ++q) {
      int m = r0 * 4 + q;
      int j = w * 32 + hf * 16 + c0;
      h_out[(size_t)(blk * 16 + m) * HID + j] = hv[hf * 4 + q];
    }
}

// ============================================================================
// k3: head: hidden = relu([h1,h2] @ w_hid^T + b_hid); out = hidden @ w_out^T + b_out
// ============================================================================
__global__ __launch_bounds__(256, 4) void k3_head(
    const float* __restrict__ h_out, const float* __restrict__ whidT,
    const float* __restrict__ b_hid, const float* __restrict__ w_out,
    const float* __restrict__ b_out, float* __restrict__ out)
{
  __shared__ float cat[8 * 512];
  __shared__ float hred[8 * 256];
  __shared__ float pred[4 * 24];
  const int tid = threadIdx.x;
  const int b0 = blockIdx.x * 8;

  for (int idx = tid; idx < 4096; idx += 256) {
    int r8 = idx >> 9, kk = idx & 511;
    float v = (kk < 256) ? h_out[(size_t)(b0 + r8) * HID + kk]
                         : h_out[(size_t)(512 + b0 + r8) * HID + (kk - 256)];
    cat[idx] = v;
  }
  __syncthreads();

  const int r = tid;
  float acc[8];
#pragma unroll
  for (int bb = 0; bb < 8; ++bb) acc[bb] = 0.f;
  for (int k = 0; k < 512; k += 4) {
    float w0 = whidT[(k + 0) * 256 + r];
    float w1 = whidT[(k + 1) * 256 + r];
    float w2 = whidT[(k + 2) * 256 + r];
    float w3 = whidT[(k + 3) * 256 + r];
#pragma unroll
    for (int bb = 0; bb < 8; ++bb) {
      f32x4 cv = *(const f32x4*)&cat[bb * 512 + k];
      acc[bb] += cv[0] * w0 + cv[1] * w1 + cv[2] * w2 + cv[3] * w3;
    }
  }
  float bh = b_hid[r];
#pragma unroll
  for (int bb = 0; bb < 8; ++bb) hred[bb * 256 + r] = fmaxf(acc[bb] + bh, 0.f);
  __syncthreads();

  const int wv = tid >> 6, l = tid & 63;
  float wo0 = w_out[0 * 256 + r], wo1 = w_out[1 * 256 + r], wo2 = w_out[2 * 256 + r];
#pragma unroll 1
  for (int bb = 0; bb < 8; ++bb) {
    float h = hred[bb * 256 + r];
    float p0 = h * wo0, p1 = h * wo1, p2 = h * wo2;
#pragma unroll
    for (int off = 32; off > 0; off >>= 1) {
      p0 += __shfl_down(p0, off, 64);
      p1 += __shfl_down(p1, off, 64);
      p2 += __shfl_down(p2, off, 64);
    }
    if (l == 0) {
      pred[wv * 24 + bb * 3 + 0] = p0;
      pred[wv * 24 + bb * 3 + 1] = p1;
      pred[wv * 24 + bb * 3 + 2] = p2;
    }
  }
  __syncthreads();
  if (tid < 24) {
    int bb = tid / 3, o = tid % 3;
    float s = pred[0 * 24 + tid] + pred[1 * 24 + tid] + pred[2 * 24 + tid] + pred[3 * 24 + tid]
              + b_out[o];
    out[(size_t)(b0 + bb) * 3 + o] = s;
  }
}

// ============================================================================
extern "C" void kernel_launch(void* const* d_in, const int* in_sizes, int n_in,
                              void* d_out, int out_size, void* d_ws, size_t ws_size,
                              hipStream_t stream) {
  (void)in_sizes; (void)n_in; (void)out_size; (void)ws_size; // needs ~105 MB ws
  const int*   s1    = (const int*)d_in[0];
  const int*   s2    = (const int*)d_in[1];
  const float* emb   = (const float*)d_in[2];
  const float* w_ih  = (const float*)d_in[3];
  const float* w_hh  = (const float*)d_in[4];
  const float* b_ih  = (const float*)d_in[5];
  const float* b_hh  = (const float*)d_in[6];
  const float* w_hid = (const float*)d_in[7];
  const float* b_hid = (const float*)d_in[8];
  const float* w_out = (const float*)d_in[9];
  const float* b_out = (const float*)d_in[10];
  char* ws = (char*)d_ws;
  unsigned short* table2 = (unsigned short*)(ws + OFF_TABLE);
  unsigned short* whhf   = (unsigned short*)(ws + OFF_WHHF);
  unsigned short* wihf   = (unsigned short*)(ws + OFF_WIHF);
  float* bcomb = (float*)(ws + OFF_BCOMB);
  float* whidT = (float*)(ws + OFF_WHIDT);
  float* h_out = (float*)(ws + OFF_HOUT);
  float* outp  = (float*)d_out;

  k0_prep<<<dim3(2052), dim3(256), 0, stream>>>(w_ih, w_hh, b_ih, b_hh, w_hid,
                                                whhf, wihf, bcomb, whidT);
  k1_table<<<dim3(782), dim3(256), 0, stream>>>(emb, wihf, bcomb, table2);
  k2_lstm<<<dim3(64), dim3(512), 0, stream>>>(s1, s2, table2, whhf, h_out);
  k3_head<<<dim3(64), dim3(256), 0, stream>>>(h_out, whidT, b_hid, w_out, b_out, outp);
}

// Round 4
// 1503.188 us; speedup vs baseline: 1.3643x; 1.0198x over previous
//
#include <hip/hip_runtime.h>
#include <stdint.h>
#include <stddef.h>

// Problem constants
#define VOCAB 50000
#define EMB   128
#define HID   256
#define G4    1024   // 4*HID
#define BATCH 512
#define SEQ   256
#define NCHAIN 1024  // 2 sequences * 512 batch

// ---------- workspace layout (bytes) ----------
#define OFF_TABLE  0UL
#define SZ_TABLE   (50000UL*1024UL*2UL)            // 102,400,000  bf16 gate table (permuted cols)
#define OFF_WHHF   (OFF_TABLE + SZ_TABLE)
#define SZ_WHHF    (512UL*512UL*2UL)               // 524,288      w_hh B-fragments bf16
#define OFF_WIHF   (OFF_WHHF + SZ_WHHF)
#define SZ_WIHF    (256UL*512UL*2UL)               // 262,144      w_ih B-fragments bf16
#define OFF_BCOMB  (OFF_WIHF + SZ_WIHF)
#define SZ_BCOMB   (1024UL*4UL)                    // combined bias (permuted)
#define OFF_WHIDT  (OFF_BCOMB + SZ_BCOMB)
#define SZ_WHIDT   (512UL*256UL*4UL)               // w_hid transposed [512][256] f32
#define OFF_HOUT   (OFF_WHIDT + SZ_WHIDT)
#define SZ_HOUT    (1024UL*256UL*4UL)              // final h per chain, f32
// total ~104.8 MB

typedef short bf16x8 __attribute__((ext_vector_type(8)));
typedef short bf16x4 __attribute__((ext_vector_type(4)));
typedef float f32x4  __attribute__((ext_vector_type(4)));
typedef float f32x2  __attribute__((ext_vector_type(2)));

__device__ __forceinline__ unsigned short f2bf(float f) {
  union { float f; uint32_t u; } v; v.f = f;
  uint32_t r = (v.u + 0x7FFFu + ((v.u >> 16) & 1u)) >> 16;
  return (unsigned short)r;
}
__device__ __forceinline__ float bf2f(unsigned short h) {
  union { float f; uint32_t u; } v; v.u = ((uint32_t)h) << 16; return v.f;
}
__device__ __forceinline__ float fast_exp2(float x) { return __builtin_amdgcn_exp2f(x); }
__device__ __forceinline__ float fast_rcp(float x)  { return __builtin_amdgcn_rcpf(x); }
#define LOG2E 1.4426950408889634f
__device__ __forceinline__ float sigm(float x) {
  return fast_rcp(1.0f + fast_exp2(-LOG2E * x));
}
__device__ __forceinline__ float tanh_(float x) {
  float e = fast_exp2(2.0f * LOG2E * x);     // exp(2x)
  return 1.0f - 2.0f * fast_rcp(e + 1.0f);   // (e-1)/(e+1)
}

// gate permutation: wave w (0..7) owns local gates i (0..127);
// original gate index = (i>>5)*256 + w*32 + (i&31)   (blocks: i,f,g,o for j in [w*32, w*32+32))
__device__ __forceinline__ int gperm(int w, int i) {
  return ((i >> 5) << 8) + (w << 5) + (i & 31);
}

// LDS swizzles (byte-XOR per G4 to break b128 same-bank columns). Index in ushorts.
__device__ __forceinline__ int hswz(int m, int k) {          // h tile: row stride 256 bf16
  return ((m * 512 + k * 2) ^ ((m & 7) << 4)) >> 1;
}
__device__ __forceinline__ int aswz(int row, int k) {        // emb tile: row stride 128 bf16
  return ((row * 256 + k * 2) ^ ((row & 7) << 4)) >> 1;
}

// Shared A/B k-placement bijection within each 32-wide k block (A and B use the SAME
// map so the MFMA contraction pairs identical true-k on both sides; dot products are
// permutation-invariant so the true HW k-map is irrelevant):
//   scatter by true k: k = hf*16 + v (hf=bit4, v=k&15) -> p = (v>>2)*8 + hf*4 + (v&3)
__device__ __forceinline__ int kplace(int k) {   // k in [0,32), returns p in [0,32)
  int v = k & 15, hf = (k >> 4) & 1;
  return ((v >> 2) << 3) + (hf << 2) + (v & 3);
}

// xg table column order within wave slice (NEW this round): storage pos = c0*8 + s,
// where s = gg*2 + hf and local gate i = (gg*2+hf)*16 + c0. This makes the k2
// elementwise phase read its 8 gate pre-activations as ONE b128 per chain.
// Only k1's staging-write position implements this; gather/copy are position-agnostic.

// ============================================================================
// k0: pack w_hh / w_ih into MFMA B-fragment layout (bf16), combined bias, w_hid^T
// ============================================================================
__global__ __launch_bounds__(256) void k0_prep(
    const float* __restrict__ w_ih, const float* __restrict__ w_hh,
    const float* __restrict__ b_ih, const float* __restrict__ b_hh,
    const float* __restrict__ w_hid,
    unsigned short* __restrict__ whhf, unsigned short* __restrict__ wihf,
    float* __restrict__ bcomb, float* __restrict__ whidT)
{
  int idx = blockIdx.x * 256 + threadIdx.x;
  if (idx < 262144) {                       // whhf: 512 frags x 512 ushorts
    int f = idx >> 9, r = idx & 511, l = r >> 3, e = r & 7;
    int w = f >> 6, nt = (f >> 3) & 7, ks = f & 7;
    int n = gperm(w, nt * 16 + (l & 15));
    int k = ks * 32 + ((e >> 2) << 4) + ((l >> 4) << 2) + (e & 3);
    whhf[idx] = f2bf(w_hh[n * HID + k]);
  } else if (idx < 262144 + 131072) {       // wihf: 256 frags x 512
    int i2 = idx - 262144;
    int f = i2 >> 9, r = i2 & 511, l = r >> 3, e = r & 7;
    int ks = f & 3, nt = (f >> 2) & 7, w = f >> 5;
    int n = gperm(w, nt * 16 + (l & 15));
    int k = ks * 32 + ((e >> 2) << 4) + ((l >> 4) << 2) + (e & 3);
    wihf[i2] = f2bf(w_ih[n * EMB + k]);
  } else if (idx < 262144 + 131072 + 1024) {
    int i2 = idx - (262144 + 131072);
    int w = i2 >> 7, ii = i2 & 127;
    int g = gperm(w, ii);
    bcomb[i2] = b_ih[g] + b_hh[g];
  } else if (idx < 262144 + 131072 + 1024 + 131072) {
    int i2 = idx - (262144 + 131072 + 1024);
    int k = i2 >> 8, rr = i2 & 255;
    whidT[i2] = w_hid[rr * 512 + k];        // w_hid [256][512] -> [512][256]
  }
}

// ============================================================================
// k1: gate table GEMM: table[v][p] = emb[v] . w_ih[G(p)] + bcomb[p]   (bf16 out)
//     M=50000 rows (64/block), N=1024 permuted cols, K=128.
// ============================================================================
__global__ __launch_bounds__(256, 4) void k1_table(
    const float* __restrict__ emb, const unsigned short* __restrict__ wihf,
    const float* __restrict__ bcomb, unsigned short* __restrict__ table2)
{
  __shared__ unsigned short a_lds[64 * 128];      // swizzled + k-placed bf16
  __shared__ unsigned short ostage[4 * 16 * 136]; // per-wave staging, padded rows
  const int tid = threadIdx.x;
  const int w = tid >> 6, l = tid & 63, r0 = l >> 4, c0 = l & 15;
  const int v0 = blockIdx.x * 64;

  // stage 64 emb rows as bf16, scattered into the SHARED k-placement map
  for (int idx = tid; idx < 8192; idx += 256) {
    int row = idx >> 7, k = idx & 127;
    int gr = v0 + row; if (gr >= VOCAB) gr = VOCAB - 1;
    float x = emb[(size_t)gr * EMB + k];
    int p = (k & ~31) + kplace(k & 31);
    a_lds[aswz(row, p)] = f2bf(x);
  }
  __syncthreads();

  bf16x8 af[4];
#pragma unroll
  for (int ks = 0; ks < 4; ++ks)
    af[ks] = *(const bf16x8*)&a_lds[aswz(w * 16 + c0, ks * 32 + r0 * 8)];

  unsigned short* ost = &ostage[w * 2176];
#pragma unroll 1
  for (int nb = 0; nb < 8; ++nb) {
    f32x4 acc[8];
#pragma unroll
    for (int nt = 0; nt < 8; ++nt) acc[nt] = (f32x4){0.f, 0.f, 0.f, 0.f};
#pragma unroll
    for (int ks = 0; ks < 4; ++ks) {
#pragma unroll
      for (int nt = 0; nt < 8; ++nt) {
        bf16x8 bv = *(const bf16x8*)(wihf + ((((nb * 8 + nt) * 4) + ks) << 9) + (l << 3));
        acc[nt] = __builtin_amdgcn_mfma_f32_16x16x32_bf16(af[ks], bv, acc[nt], 0, 0, 0);
      }
    }
    // NEW column order: local gate (nt,c0) stored at pos c0*8 + nt
#pragma unroll
    for (int nt = 0; nt < 8; ++nt) {
      float bias = bcomb[nb * 128 + nt * 16 + c0];
#pragma unroll
      for (int reg = 0; reg < 4; ++reg)
        ost[(r0 * 4 + reg) * 136 + c0 * 8 + nt] = f2bf(acc[nt][reg] + bias);
    }
    asm volatile("s_waitcnt lgkmcnt(0)" ::: "memory");
#pragma unroll
    for (int i = 0; i < 4; ++i) {
      int idx = i * 64 + l;
      int row = idx >> 4, seg = idx & 15;
      int v = v0 + w * 16 + row;
      if (v < VOCAB)
        *(bf16x8*)(table2 + (size_t)v * 1024 + nb * 128 + seg * 8) =
            *(const bf16x8*)&ost[row * 136 + seg * 8];
    }
    __syncthreads();
  }
}

// ============================================================================
// k2: the recurrence. 64 blocks x 512 threads (8 waves). Block owns 16 chains.
//     Wave w owns gates {i,f,g,o} for j in [w*32, w*32+32) = 8 n-tiles of 16.
//     Weight residency (frag f = nt*8+ks, 64 frags/wave, 1 KB each):
//       nt 0..3            (32 frags): VGPR/AGPR-resident (128 regs; arch+acc
//                                      unified file splits 128/128 -- OK)
//       nt4 all, nt5 ks0-4 (13 frags): LDS-resident (104 KB)
//       nt5 ks5-7, nt6, nt7 (19 frags): streamed from L2, 3-slot rotating reg
//                                       buffer, 2-ks lookahead
//     xg gather for t+1 issued at TOP of step t (covered by MFMA loop);
//     elementwise reads xg as ONE ds_read_b128 per chain (new column order).
// ============================================================================
__global__ __launch_bounds__(512) void k2_lstm(
    const int* __restrict__ s1, const int* __restrict__ s2,
    const unsigned short* __restrict__ table2,
    const unsigned short* __restrict__ whhf,
    float* __restrict__ h_out)
{
  __shared__ unsigned short h_lds[16 * 256];      // 8 KB  swizzled + k-placed bf16
  __shared__ unsigned short tok_lds[16 * 256];    // 8 KB  tokens as u16
  __shared__ unsigned short xg_lds[8 * 16 * 136]; // 34.8 KB per-wave xg slices
  __shared__ unsigned short w_lds[8 * 13 * 512];  // 104 KB  13 weight frags/wave

  const int tid = threadIdx.x;
  const int w = tid >> 6, l = tid & 63;
  const int r0 = l >> 4, c0 = l & 15;
  const int blk = blockIdx.x;
  const int xg_chain = l >> 2;        // 4 lanes per chain
  const int xg_seg = l & 3;

  // preload tokens (u16) + zero h
  for (int idx = tid; idx < 4096; idx += 512) {
    int chain = blk * 16 + (idx >> 8);
    const int* sp = (chain >= 512) ? s2 : s1;
    tok_lds[idx] = (unsigned short)sp[(chain & 511) * SEQ + (idx & 255)];
    h_lds[idx] = 0;
  }

  const unsigned short* whW = whhf + w * 32768;  // this wave's 64 frags
  unsigned short* wl = &w_lds[w * 6656];

  // stage LDS-resident frags: j<8 -> nt4 ks=j ; j>=8 -> nt5 ks=j-8 (ks0..4)
#pragma unroll
  for (int j = 0; j < 13; ++j) {
    int frag = (j < 8) ? (4 * 8 + j) : (5 * 8 + (j - 8));
    bf16x8 v = *(const bf16x8*)(whW + (frag << 9) + (l << 3));
    *(bf16x8*)&wl[j * 512 + (l << 3)] = v;
  }

  // VGPR/AGPR-resident frags: nt 0..3, all ks (128 regs)
  bf16x8 whr[32];
#pragma unroll
  for (int f = 0; f < 32; ++f)
    whr[f] = *(const bf16x8*)(whW + (f << 9) + (l << 3));

  __syncthreads();

  // streamed rotating buffer: batch p (=ks p): slot p%3.
  // slot contents: [0]=nt6 ksp, [1]=nt7 ksp, [2]=nt5 ksp (p>=5 only)
  bf16x8 sbuf[3][3];
#define ISSUE_BATCH(P, S)                                                         \
  do {                                                                            \
    sbuf[S][0] = *(const bf16x8*)(whW + ((6 * 8 + (P)) << 9) + (l << 3));         \
    sbuf[S][1] = *(const bf16x8*)(whW + ((7 * 8 + (P)) << 9) + (l << 3));         \
    if ((P) >= 5)                                                                 \
      sbuf[S][2] = *(const bf16x8*)(whW + ((5 * 8 + (P)) << 9) + (l << 3));       \
  } while (0)

  // prologue: first gather + first two stream batches
  bf16x8 X0, X1, X2, X3;
  {
    int tok0 = tok_lds[xg_chain * 256 + 0];
    const unsigned short* xr = table2 + (size_t)tok0 * 1024 + w * 128;
    X0 = *(const bf16x8*)(xr + (xg_seg) * 8);
    X1 = *(const bf16x8*)(xr + (xg_seg + 4) * 8);
    X2 = *(const bf16x8*)(xr + (xg_seg + 8) * 8);
    X3 = *(const bf16x8*)(xr + (xg_seg + 12) * 8);
  }
  ISSUE_BATCH(0, 0);
  ISSUE_BATCH(1, 1);

  float c_st[8], hv[8];
#pragma unroll
  for (int i = 0; i < 8; ++i) { c_st[i] = 0.f; hv[i] = 0.f; }

#pragma unroll 1
  for (int t = 0; t < SEQ; ++t) {
    // store this step's xg into per-wave LDS slice (chunk cidx covers pos [cidx*8, +8))
    {
      int base = w * 2176 + xg_chain * 136;
      *(bf16x8*)&xg_lds[base + (xg_seg) * 8] = X0;
      *(bf16x8*)&xg_lds[base + (xg_seg + 4) * 8] = X1;
      *(bf16x8*)&xg_lds[base + (xg_seg + 8) * 8] = X2;
      *(bf16x8*)&xg_lds[base + (xg_seg + 12) * 8] = X3;
    }
    // issue NEXT step's gather now -- covered by the whole MFMA loop
    if (t + 1 < SEQ) {
      int tok = tok_lds[xg_chain * 256 + (t + 1)];
      const unsigned short* xr = table2 + (size_t)tok * 1024 + w * 128;
      X0 = *(const bf16x8*)(xr + (xg_seg) * 8);
      X1 = *(const bf16x8*)(xr + (xg_seg + 4) * 8);
      X2 = *(const bf16x8*)(xr + (xg_seg + 8) * 8);
      X3 = *(const bf16x8*)(xr + (xg_seg + 12) * 8);
    }

    f32x4 acc[8];
#pragma unroll
    for (int nt = 0; nt < 8; ++nt) acc[nt] = (f32x4){0.f, 0.f, 0.f, 0.f};

#pragma unroll
    for (int p = 0; p < 8; ++p) {
      if (p + 2 <= 7) { ISSUE_BATCH(p + 2, (p + 2) % 3); }
      bf16x8 av = *(const bf16x8*)&h_lds[hswz(c0, p * 32 + r0 * 8)];
      acc[0] = __builtin_amdgcn_mfma_f32_16x16x32_bf16(av, whr[0 * 8 + p], acc[0], 0, 0, 0);
      acc[1] = __builtin_amdgcn_mfma_f32_16x16x32_bf16(av, whr[1 * 8 + p], acc[1], 0, 0, 0);
      acc[2] = __builtin_amdgcn_mfma_f32_16x16x32_bf16(av, whr[2 * 8 + p], acc[2], 0, 0, 0);
      acc[3] = __builtin_amdgcn_mfma_f32_16x16x32_bf16(av, whr[3 * 8 + p], acc[3], 0, 0, 0);
      {
        bf16x8 bv = *(const bf16x8*)&wl[p * 512 + (l << 3)];
        acc[4] = __builtin_amdgcn_mfma_f32_16x16x32_bf16(av, bv, acc[4], 0, 0, 0);
      }
      if (p < 5) {
        bf16x8 bv = *(const bf16x8*)&wl[(8 + p) * 512 + (l << 3)];
        acc[5] = __builtin_amdgcn_mfma_f32_16x16x32_bf16(av, bv, acc[5], 0, 0, 0);
      } else {
        acc[5] = __builtin_amdgcn_mfma_f32_16x16x32_bf16(av, sbuf[p % 3][2], acc[5], 0, 0, 0);
      }
      acc[6] = __builtin_amdgcn_mfma_f32_16x16x32_bf16(av, sbuf[p % 3][0], acc[6], 0, 0, 0);
      acc[7] = __builtin_amdgcn_mfma_f32_16x16x32_bf16(av, sbuf[p % 3][1], acc[7], 0, 0, 0);
    }

    // issue next step's first two stream batches (covered by elementwise+barriers)
    if (t + 1 < SEQ) {
      ISSUE_BATCH(0, 0);
      ISSUE_BATCH(1, 1);
    }

    // gates -> c,h. xg read: ONE b128 per chain (new column order pos = c0*8 + s)
    asm volatile("s_waitcnt lgkmcnt(0)" ::: "memory");
#pragma unroll
    for (int q = 0; q < 4; ++q) {
      int m = r0 * 4 + q;
      bf16x8 xv = *(const bf16x8*)&xg_lds[w * 2176 + m * 136 + c0 * 8];
#pragma unroll
      for (int hf = 0; hf < 2; ++hf) {
        float iv = sigm(acc[0 + hf][q] + bf2f((unsigned short)xv[0 + hf]));
        float fv = sigm(acc[2 + hf][q] + bf2f((unsigned short)xv[2 + hf]));
        float gv = tanh_(acc[4 + hf][q] + bf2f((unsigned short)xv[4 + hf]));
        float ov = sigm(acc[6 + hf][q] + bf2f((unsigned short)xv[6 + hf]));
        int cs = hf * 4 + q;
        float c = fv * c_st[cs] + iv * gv;
        c_st[cs] = c;
        hv[cs] = ov * tanh_(c);
      }
    }

    __syncthreads();   // all waves done reading h(t-1)
#pragma unroll
    for (int hf = 0; hf < 2; ++hf)
#pragma unroll
      for (int q = 0; q < 4; ++q) {
        int m = r0 * 4 + q;
        // original j = w*32 + hf*16 + c0 -> SHARED k-placement within block w
        int qk = (w << 5) + ((c0 >> 2) << 3) + (hf << 2) + (c0 & 3);
        h_lds[hswz(m, qk)] = f2bf(hv[hf * 4 + q]);
      }
    __syncthreads();   // h(t) visible
  }

  // final h (f32, pre-rounding) -> h_out[chain][j]
#pragma unroll
  for (int hf = 0; hf < 2; ++hf)
#pragma unroll
    for (int q = 0; q < 4; ++q) {
      int m = r0 * 4 + q;
      int j = w * 32 + hf * 16 + c0;
      h_out[(size_t)(blk * 16 + m) * HID + j] = hv[hf * 4 + q];
    }
#undef ISSUE_BATCH
}

// ============================================================================
// k3: head: hidden = relu([h1,h2] @ w_hid^T + b_hid); out = hidden @ w_out^T + b_out
// ============================================================================
__global__ __launch_bounds__(256, 4) void k3_head(
    const float* __restrict__ h_out, const float* __restrict__ whidT,
    const float* __restrict__ b_hid, const float* __restrict__ w_out,
    const float* __restrict__ b_out, float* __restrict__ out)
{
  __shared__ float cat[8 * 512];
  __shared__ float hred[8 * 256];
  __shared__ float pred[4 * 24];
  const int tid = threadIdx.x;
  const int b0 = blockIdx.x * 8;

  for (int idx = tid; idx < 4096; idx += 256) {
    int r8 = idx >> 9, kk = idx & 511;
    float v = (kk < 256) ? h_out[(size_t)(b0 + r8) * HID + kk]
                         : h_out[(size_t)(512 + b0 + r8) * HID + (kk - 256)];
    cat[idx] = v;
  }
  __syncthreads();

  const int r = tid;
  float acc[8];
#pragma unroll
  for (int bb = 0; bb < 8; ++bb) acc[bb] = 0.f;
  for (int k = 0; k < 512; k += 4) {
    float w0 = whidT[(k + 0) * 256 + r];
    float w1 = whidT[(k + 1) * 256 + r];
    float w2 = whidT[(k + 2) * 256 + r];
    float w3 = whidT[(k + 3) * 256 + r];
#pragma unroll
    for (int bb = 0; bb < 8; ++bb) {
      f32x4 cv = *(const f32x4*)&cat[bb * 512 + k];
      acc[bb] += cv[0] * w0 + cv[1] * w1 + cv[2] * w2 + cv[3] * w3;
    }
  }
  float bh = b_hid[r];
#pragma unroll
  for (int bb = 0; bb < 8; ++bb) hred[bb * 256 + r] = fmaxf(acc[bb] + bh, 0.f);
  __syncthreads();

  const int wv = tid >> 6, l = tid & 63;
  float wo0 = w_out[0 * 256 + r], wo1 = w_out[1 * 256 + r], wo2 = w_out[2 * 256 + r];
#pragma unroll 1
  for (int bb = 0; bb < 8; ++bb) {
    float h = hred[bb * 256 + r];
    float p0 = h * wo0, p1 = h * wo1, p2 = h * wo2;
#pragma unroll
    for (int off = 32; off > 0; off >>= 1) {
      p0 += __shfl_down(p0, off, 64);
      p1 += __shfl_down(p1, off, 64);
      p2 += __shfl_down(p2, off, 64);
    }
    if (l == 0) {
      pred[wv * 24 + bb * 3 + 0] = p0;
      pred[wv * 24 + bb * 3 + 1] = p1;
      pred[wv * 24 + bb * 3 + 2] = p2;
    }
  }
  __syncthreads();
  if (tid < 24) {
    int bb = tid / 3, o = tid % 3;
    float s = pred[0 * 24 + tid] + pred[1 * 24 + tid] + pred[2 * 24 + tid] + pred[3 * 24 + tid]
              + b_out[o];
    out[(size_t)(b0 + bb) * 3 + o] = s;
  }
}

// ============================================================================
extern "C" void kernel_launch(void* const* d_in, const int* in_sizes, int n_in,
                              void* d_out, int out_size, void* d_ws, size_t ws_size,
                              hipStream_t stream) {
  (void)in_sizes; (void)n_in; (void)out_size; (void)ws_size; // needs ~105 MB ws
  const int*   s1    = (const int*)d_in[0];
  const int*   s2    = (const int*)d_in[1];
  const float* emb   = (const float*)d_in[2];
  const float* w_ih  = (const float*)d_in[3];
  const float* w_hh  = (const float*)d_in[4];
  const float* b_ih  = (const float*)d_in[5];
  const float* b_hh  = (const float*)d_in[6];
  const float* w_hid = (const float*)d_in[7];
  const float* b_hid = (const float*)d_in[8];
  const float* w_out = (const float*)d_in[9];
  const float* b_out = (const float*)d_in[10];
  char* ws = (char*)d_ws;
  unsigned short* table2 = (unsigned short*)(ws + OFF_TABLE);
  unsigned short* whhf   = (unsigned short*)(ws + OFF_WHHF);
  unsigned short* wihf   = (unsigned short*)(ws + OFF_WIHF);
  float* bcomb = (float*)(ws + OFF_BCOMB);
  float* whidT = (float*)(ws + OFF_WHIDT);
  float* h_out = (float*)(ws + OFF_HOUT);
  float* outp  = (float*)d_out;

  k0_prep<<<dim3(2052), dim3(256), 0, stream>>>(w_ih, w_hh, b_ih, b_hh, w_hid,
                                                whhf, wihf, bcomb, whidT);
  k1_table<<<dim3(782), dim3(256), 0, stream>>>(emb, wihf, bcomb, table2);
  k2_lstm<<<dim3(64), dim3(512), 0, stream>>>(s1, s2, table2, whhf, h_out);
  k3_head<<<dim3(64), dim3(256), 0, stream>>>(h_out, whidT, b_hid, w_out, b_out, outp);
}